// Round 1
// baseline (40.267 us; speedup 1.0000x reference)
//
#include <hip/hip_runtime.h>

// RandomPool: out[b,c,i,j] = x[b, c, 2*i + sel/2, 2*j + sel%2]
// sel = select_idx[b / T, i*56 + j],  B=32, C=128, H=W=112, side=56, K=STRIDE=2, T=8.
// Memory-bound gather: ~51 MB out, ~51-103 MB in. One thread = 4 outputs (float4 store).

#define B_ 32
#define C_ 128
#define H_ 112
#define W_ 112
#define SIDE_ 56
#define T_ 8
#define NPATCH_ (SIDE_ * SIDE_)   // 3136

__global__ __launch_bounds__(256) void randompool_kernel(
    const float* __restrict__ x,
    const int* __restrict__ sel,
    float* __restrict__ out)
{
    int idx = blockIdx.x * blockDim.x + threadIdx.x;  // one per quad of outputs
    // total quads = B*C*SIDE*(SIDE/4) = 32*128*56*14 = 3,211,264 (grid exact)
    int j4 = idx % (SIDE_ / 4);
    int v  = idx / (SIDE_ / 4);
    int i  = v % SIDE_;
    v     /= SIDE_;
    int c  = v % C_;
    int b  = v / C_;

    int clip = b / T_;  // b >> 3
    // 16B-aligned: clip*3136, i*56, j4*4 all multiples of 4 ints
    const int4 s4 = *reinterpret_cast<const int4*>(sel + clip * NPATCH_ + i * SIDE_ + j4 * 4);

    const float* xp = x + ((b * C_ + c) * H_) * W_;  // max ~51.4M, fits int32
    const int r0 = i * 2;
    const int c0 = j4 * 8;  // (j4*4)*2

    float4 o;
    { int s = s4.x; o.x = xp[(r0 + (s >> 1)) * W_ + c0 + 0 + (s & 1)]; }
    { int s = s4.y; o.y = xp[(r0 + (s >> 1)) * W_ + c0 + 2 + (s & 1)]; }
    { int s = s4.z; o.z = xp[(r0 + (s >> 1)) * W_ + c0 + 4 + (s & 1)]; }
    { int s = s4.w; o.w = xp[(r0 + (s >> 1)) * W_ + c0 + 6 + (s & 1)]; }

    *reinterpret_cast<float4*>(out + ((b * C_ + c) * SIDE_ + i) * SIDE_ + j4 * 4) = o;
}

extern "C" void kernel_launch(void* const* d_in, const int* in_sizes, int n_in,
                              void* d_out, int out_size, void* d_ws, size_t ws_size,
                              hipStream_t stream) {
    const float* x   = (const float*)d_in[0];
    const int*   sel = (const int*)d_in[1];
    float*       out = (float*)d_out;

    const int total_quads = B_ * C_ * SIDE_ * (SIDE_ / 4);  // 3,211,264
    const int block = 256;
    const int grid  = total_quads / block;                   // 12,544 exact
    randompool_kernel<<<grid, block, 0, stream>>>(x, sel, out);
}